// Round 1
// baseline (335.692 us; speedup 1.0000x reference)
//
#include <hip/hip_runtime.h>
#include <hip/hip_bf16.h>
#include <stdint.h>

#define BROWS 16384
#define DIM   256
#define BM    128
#define BN    128
#define BK    128
#define NBM   (BROWS / BM)      // 128 row blocks
#define NCHUNK 256              // 64-wide column chunks per row

typedef __attribute__((ext_vector_type(8))) short bf16x8;
typedef __attribute__((ext_vector_type(4))) float f32x4;

__device__ __forceinline__ float b2f(unsigned short u) {
  return __uint_as_float(((unsigned)u) << 16);
}
__device__ __forceinline__ unsigned short f2b(float f) {
  unsigned u = __float_as_uint(f);
  u += 0x7fffu + ((u >> 16) & 1u);   // RNE
  return (unsigned short)(u >> 16);
}

__device__ __forceinline__ void gload_lds16(const void* g, void* l) {
  __builtin_amdgcn_global_load_lds(
      (const __attribute__((address_space(1))) void*)g,
      (__attribute__((address_space(3))) void*)l, 16, 0, 0);
}

// ---------------- Kernel A: row-normalize f32 -> bf16 ----------------
// one wave per row; lane loads float4 (16B), full-row reduce, write ushort4
__global__ void normalize_rows(const float* __restrict__ in,
                               unsigned short* __restrict__ out) {
  int row  = blockIdx.x * 4 + (threadIdx.x >> 6);
  int lane = threadIdx.x & 63;
  float4 v = *(reinterpret_cast<const float4*>(in + (size_t)row * DIM) + lane);
  float ss = v.x * v.x + v.y * v.y + v.z * v.z + v.w * v.w;
#pragma unroll
  for (int m = 1; m < 64; m <<= 1) ss += __shfl_xor(ss, m);
  float r = rsqrtf(ss);
  ushort4 o;
  o.x = f2b(v.x * r);
  o.y = f2b(v.y * r);
  o.z = f2b(v.z * r);
  o.w = f2b(v.w * r);
  *(reinterpret_cast<ushort4*>(out + (size_t)row * DIM) + lane) = o;
}

// ---------------- Kernel B: fused GEMM + exp + per-row partial sums ----------------
// C-tile 128x128, 4 waves in 2x2 (each wave 64x64), 16x16x32 bf16 MFMA.
// Epilogue: per-row sum of exp over this tile's 64-col wave chunk ->
// partial[row*NCHUNK + bn*2+wc]  (every slot written exactly once; no atomics)
__global__ __launch_bounds__(256, 2) void gemm_expsum(
    const unsigned short* __restrict__ A,   // ohat [BROWS][DIM]
    const unsigned short* __restrict__ Bm,  // that [BROWS][DIM] (rows = logits cols)
    float* __restrict__ partial) {
  __shared__ unsigned short As[BM * BK];  // 32 KB
  __shared__ unsigned short Bs[BN * BK];  // 32 KB

  int tid  = threadIdx.x;
  int lane = tid & 63;
  int wid  = tid >> 6;
  int wr   = wid >> 1;      // wave row 0..1
  int wc   = wid & 1;       // wave col 0..1
  int bm   = blockIdx.x & (NBM - 1);
  int bn   = blockIdx.x >> 7;

  f32x4 acc[4][4];
#pragma unroll
  for (int m = 0; m < 4; ++m)
#pragma unroll
    for (int n = 0; n < 4; ++n) acc[m][n] = (f32x4){0.f, 0.f, 0.f, 0.f};

  const int r16 = tid >> 4;        // 0..15
  const int c8  = (tid & 15) * 8;  // element col within the BK slice

#pragma unroll
  for (int kt = 0; kt < DIM / BK; ++kt) {
    const unsigned short* gA = A  + (size_t)bm * BM * DIM + kt * BK;
    const unsigned short* gB = Bm + (size_t)bn * BN * DIM + kt * BK;
    // stage 32KB each of A,B: 8 passes x (256 thr x 16B). LDS dest is
    // wave-uniform base + lane*16 (hardware rule); global addr is per-lane.
#pragma unroll
    for (int p = 0; p < 8; ++p) {
      int row = p * 16 + r16;
      gload_lds16(gA + (size_t)row * DIM + c8, (char*)As + p * 4096 + wid * 1024);
      gload_lds16(gB + (size_t)row * DIM + c8, (char*)Bs + p * 4096 + wid * 1024);
    }
    __syncthreads();

#pragma unroll
    for (int kk = 0; kk < 4; ++kk) {
      const int fr = lane & 15;
      const int fk = kk * 32 + (lane >> 4) * 8;
      bf16x8 af[4], bf[4];
#pragma unroll
      for (int m = 0; m < 4; ++m)
        af[m] = *reinterpret_cast<const bf16x8*>(&As[(wr * 64 + m * 16 + fr) * BK + fk]);
#pragma unroll
      for (int n = 0; n < 4; ++n)
        bf[n] = *reinterpret_cast<const bf16x8*>(&Bs[(wc * 64 + n * 16 + fr) * BK + fk]);
#pragma unroll
      for (int m = 0; m < 4; ++m)
#pragma unroll
        for (int n = 0; n < 4; ++n)
          acc[m][n] = __builtin_amdgcn_mfma_f32_16x16x32_bf16(af[m], bf[n], acc[m][n], 0, 0, 0);
    }
    __syncthreads();
  }

  // ---- epilogue: logits bounded in [-1,1] -> plain exp, no max needed ----
  // C/D layout: col = lane&15, row = (lane>>4)*4 + reg
  float esum[4][4];
#pragma unroll
  for (int m = 0; m < 4; ++m)
#pragma unroll
    for (int r = 0; r < 4; ++r) {
      float s = 0.f;
#pragma unroll
      for (int n = 0; n < 4; ++n) s += __expf(acc[m][n][r]);
      esum[m][r] = s;
    }
  // reduce over the 16 fragment columns (lane&15)
#pragma unroll
  for (int m = 0; m < 4; ++m)
#pragma unroll
    for (int r = 0; r < 4; ++r) {
      float s = esum[m][r];
      s += __shfl_xor(s, 1);
      s += __shfl_xor(s, 2);
      s += __shfl_xor(s, 4);
      s += __shfl_xor(s, 8);
      esum[m][r] = s;
    }
  if ((lane & 15) == 0) {
    int sub   = lane >> 4;              // 0..3
    int chunk = (bn << 1) | wc;         // 0..255
    int rbase = bm * BM + wr * 64;
#pragma unroll
    for (int m = 0; m < 4; ++m)
#pragma unroll
      for (int r = 0; r < 4; ++r)
        partial[(size_t)(rbase + m * 16 + sub * 4 + r) * NCHUNK + chunk] = esum[m][r];
  }
}

// ---------------- Kernel C: per-row finish: log(sum) - diag ----------------
__global__ void row_finish(const unsigned short* __restrict__ ohat,
                           const unsigned short* __restrict__ that,
                           const float* __restrict__ partial,
                           float* __restrict__ rowloss) {
  int row  = blockIdx.x * 4 + (threadIdx.x >> 6);
  int lane = threadIdx.x & 63;
  ushort4 ov = *(reinterpret_cast<const ushort4*>(ohat + (size_t)row * DIM) + lane);
  ushort4 tv = *(reinterpret_cast<const ushort4*>(that + (size_t)row * DIM) + lane);
  float d = b2f(ov.x) * b2f(tv.x) + b2f(ov.y) * b2f(tv.y) +
            b2f(ov.z) * b2f(tv.z) + b2f(ov.w) * b2f(tv.w);
  float4 p = *(reinterpret_cast<const float4*>(partial + (size_t)row * NCHUNK) + lane);
  float s = p.x + p.y + p.z + p.w;
#pragma unroll
  for (int m = 1; m < 64; m <<= 1) {
    d += __shfl_xor(d, m);
    s += __shfl_xor(s, m);
  }
  if (lane == 0) rowloss[row] = logf(s) - d;
}

// ---------------- Kernel D: mean over rows -> d_out[0] ----------------
__global__ void final_reduce(const float* __restrict__ rl, float* __restrict__ out) {
  __shared__ float sm[16];
  float s = 0.f;
  for (int i = threadIdx.x; i < BROWS; i += 1024) s += rl[i];
#pragma unroll
  for (int m = 1; m < 64; m <<= 1) s += __shfl_xor(s, m);
  int wid = threadIdx.x >> 6, lane = threadIdx.x & 63;
  if (lane == 0) sm[wid] = s;
  __syncthreads();
  if (wid == 0) {
    float v = (lane < 16) ? sm[lane] : 0.f;
#pragma unroll
    for (int m = 1; m < 16; m <<= 1) v += __shfl_xor(v, m);
    if (lane == 0) out[0] = v / (float)BROWS;
  }
}

extern "C" void kernel_launch(void* const* d_in, const int* in_sizes, int n_in,
                              void* d_out, int out_size, void* d_ws, size_t ws_size,
                              hipStream_t stream) {
  const float* outputs = (const float*)d_in[0];
  const float* targets = (const float*)d_in[1];
  float* out = (float*)d_out;
  char* ws = (char*)d_ws;

  unsigned short* ohat = (unsigned short*)ws;                                   // 8 MB
  unsigned short* that = (unsigned short*)(ws + (size_t)8 * 1024 * 1024);       // 8 MB
  float* partial       = (float*)(ws + (size_t)16 * 1024 * 1024);               // 16 MB
  float* rowloss       = (float*)(ws + (size_t)32 * 1024 * 1024);               // 64 KB

  normalize_rows<<<BROWS / 4, 256, 0, stream>>>(outputs, ohat);
  normalize_rows<<<BROWS / 4, 256, 0, stream>>>(targets, that);
  gemm_expsum<<<NBM * (BROWS / BN), 256, 0, stream>>>(ohat, that, partial);
  row_finish<<<BROWS / 4, 256, 0, stream>>>(ohat, that, partial, rowloss);
  final_reduce<<<1, 1024, 0, stream>>>(rowloss, out);
}

// Round 2
// 198.322 us; speedup vs baseline: 1.6927x; 1.6927x over previous
//
#include <hip/hip_runtime.h>
#include <hip/hip_bf16.h>
#include <stdint.h>

#define BROWS 16384
#define DIM   256
#define BM    128
#define BN    128
#define BK    64
#define NBM   (BROWS / BM)      // 128 row blocks
#define NCHUNK 256              // 64-wide column chunks per row

typedef __attribute__((ext_vector_type(8))) short bf16x8;
typedef __attribute__((ext_vector_type(4))) float f32x4;

__device__ __forceinline__ float b2f(unsigned short u) {
  return __uint_as_float(((unsigned)u) << 16);
}
__device__ __forceinline__ unsigned short f2b(float f) {
  unsigned u = __float_as_uint(f);
  u += 0x7fffu + ((u >> 16) & 1u);   // RNE
  return (unsigned short)(u >> 16);
}

__device__ __forceinline__ void gload_lds16(const void* g, void* l) {
  __builtin_amdgcn_global_load_lds(
      (const __attribute__((address_space(1))) void*)g,
      (__attribute__((address_space(3))) void*)l, 16, 0, 0);
}

// ---------------- Kernel A: row-normalize f32 -> bf16 ----------------
__global__ void normalize_rows(const float* __restrict__ in,
                               unsigned short* __restrict__ out) {
  int row  = blockIdx.x * 4 + (threadIdx.x >> 6);
  int lane = threadIdx.x & 63;
  float4 v = *(reinterpret_cast<const float4*>(in + (size_t)row * DIM) + lane);
  float ss = v.x * v.x + v.y * v.y + v.z * v.z + v.w * v.w;
#pragma unroll
  for (int m = 1; m < 64; m <<= 1) ss += __shfl_xor(ss, m);
  float r = rsqrtf(ss);
  ushort4 o;
  o.x = f2b(v.x * r);
  o.y = f2b(v.y * r);
  o.z = f2b(v.z * r);
  o.w = f2b(v.w * r);
  *(reinterpret_cast<ushort4*>(out + (size_t)row * DIM) + lane) = o;
}

// ---------------- Kernel B: fused GEMM + exp + per-row partial sums ----------------
// C-tile 128x128, 4 waves 2x2 (each wave 64x64), 16x16x32 bf16 MFMA, BK=64.
// LDS: linear dest for global_load_lds; bank-conflict fix via pre-swizzled
// GLOBAL source granule (g ^= row&7 on 16B granules) + same XOR on read.
__global__ __launch_bounds__(256, 4) void gemm_expsum(
    const unsigned short* __restrict__ A,   // ohat [BROWS][DIM]
    const unsigned short* __restrict__ Bm,  // that [BROWS][DIM] (rows = logits cols)
    float* __restrict__ partial) {
  __shared__ unsigned short As[BM * BK];  // 16 KB
  __shared__ unsigned short Bs[BN * BK];  // 16 KB

  int tid  = threadIdx.x;
  int lane = tid & 63;
  int wid  = tid >> 6;
  int wr   = wid >> 1;      // wave row 0..1
  int wc   = wid & 1;       // wave col 0..1
  int bm   = blockIdx.x & (NBM - 1);
  int bn   = blockIdx.x >> 7;

  f32x4 acc[4][4];
#pragma unroll
  for (int m = 0; m < 4; ++m)
#pragma unroll
    for (int n = 0; n < 4; ++n) acc[m][n] = (f32x4){0.f, 0.f, 0.f, 0.f};

  const int srow = tid >> 3;   // 0..31: row within a 32-row staging pass
  const int sg   = tid & 7;    // 16B granule within the 64-elem row

  const unsigned short* gA = A  + (size_t)bm * BM * DIM;
  const unsigned short* gB = Bm + (size_t)bn * BN * DIM;

#pragma unroll
  for (int kt = 0; kt < DIM / BK; ++kt) {   // 4 K-steps
    // stage 16KB each of A,B: 4 passes x (256 thr x 16B) = 32 rows/pass.
    // LDS dest is linear (wave-uniform base + lane*16); the SOURCE granule
    // carries the swizzle: LDS granule h of row r holds global granule h^(r&7).
#pragma unroll
    for (int p = 0; p < 4; ++p) {
      int row  = p * 32 + srow;
      int goff = kt * BK + ((sg ^ (row & 7)) << 3);  // element offset in the row
      gload_lds16(gA + (size_t)row * DIM + goff, (char*)As + p * 4096 + wid * 1024);
      gload_lds16(gB + (size_t)row * DIM + goff, (char*)Bs + p * 4096 + wid * 1024);
    }
    __syncthreads();

    const int fr = lane & 15;
#pragma unroll
    for (int kk = 0; kk < 2; ++kk) {
      int gk  = kk * 4 + (lane >> 4);          // wanted global granule (0..7)
      int swg = ((gk ^ (fr & 7)) << 3);        // swizzled element offset in row
      bf16x8 af[4], bfr[4];
#pragma unroll
      for (int m = 0; m < 4; ++m)
        af[m] = *reinterpret_cast<const bf16x8*>(&As[(wr * 64 + m * 16 + fr) * BK + swg]);
#pragma unroll
      for (int n = 0; n < 4; ++n)
        bfr[n] = *reinterpret_cast<const bf16x8*>(&Bs[(wc * 64 + n * 16 + fr) * BK + swg]);
#pragma unroll
      for (int m = 0; m < 4; ++m)
#pragma unroll
        for (int n = 0; n < 4; ++n)
          acc[m][n] = __builtin_amdgcn_mfma_f32_16x16x32_bf16(af[m], bfr[n], acc[m][n], 0, 0, 0);
    }
    __syncthreads();
  }

  // ---- epilogue: logits bounded in [-1,1] -> plain exp, no max needed ----
  // C/D layout: col = lane&15, row = (lane>>4)*4 + reg
  float esum[4][4];
#pragma unroll
  for (int m = 0; m < 4; ++m)
#pragma unroll
    for (int r = 0; r < 4; ++r) {
      float s = 0.f;
#pragma unroll
      for (int n = 0; n < 4; ++n) s += __expf(acc[m][n][r]);
      esum[m][r] = s;
    }
#pragma unroll
  for (int m = 0; m < 4; ++m)
#pragma unroll
    for (int r = 0; r < 4; ++r) {
      float s = esum[m][r];
      s += __shfl_xor(s, 1);
      s += __shfl_xor(s, 2);
      s += __shfl_xor(s, 4);
      s += __shfl_xor(s, 8);
      esum[m][r] = s;
    }
  if ((lane & 15) == 0) {
    int sub   = lane >> 4;              // 0..3
    int chunk = (bn << 1) | wc;         // 0..255
    int rbase = bm * BM + wr * 64;
#pragma unroll
    for (int m = 0; m < 4; ++m)
#pragma unroll
      for (int r = 0; r < 4; ++r)
        partial[(size_t)(rbase + m * 16 + sub * 4 + r) * NCHUNK + chunk] = esum[m][r];
  }
}

// ---------------- Kernel C: per-row finish: log(sum) - diag ----------------
__global__ void row_finish(const unsigned short* __restrict__ ohat,
                           const unsigned short* __restrict__ that,
                           const float* __restrict__ partial,
                           float* __restrict__ rowloss) {
  int row  = blockIdx.x * 4 + (threadIdx.x >> 6);
  int lane = threadIdx.x & 63;
  ushort4 ov = *(reinterpret_cast<const ushort4*>(ohat + (size_t)row * DIM) + lane);
  ushort4 tv = *(reinterpret_cast<const ushort4*>(that + (size_t)row * DIM) + lane);
  float d = b2f(ov.x) * b2f(tv.x) + b2f(ov.y) * b2f(tv.y) +
            b2f(ov.z) * b2f(tv.z) + b2f(ov.w) * b2f(tv.w);
  float4 p = *(reinterpret_cast<const float4*>(partial + (size_t)row * NCHUNK) + lane);
  float s = p.x + p.y + p.z + p.w;
#pragma unroll
  for (int m = 1; m < 64; m <<= 1) {
    d += __shfl_xor(d, m);
    s += __shfl_xor(s, m);
  }
  if (lane == 0) rowloss[row] = logf(s) - d;
}

// ---------------- Kernel D: mean over rows -> d_out[0] ----------------
__global__ void final_reduce(const float* __restrict__ rl, float* __restrict__ out) {
  __shared__ float sm[16];
  float s = 0.f;
  for (int i = threadIdx.x; i < BROWS; i += 1024) s += rl[i];
#pragma unroll
  for (int m = 1; m < 64; m <<= 1) s += __shfl_xor(s, m);
  int wid = threadIdx.x >> 6, lane = threadIdx.x & 63;
  if (lane == 0) sm[wid] = s;
  __syncthreads();
  if (wid == 0) {
    float v = (lane < 16) ? sm[lane] : 0.f;
#pragma unroll
    for (int m = 1; m < 16; m <<= 1) v += __shfl_xor(v, m);
    if (lane == 0) out[0] = v / (float)BROWS;
  }
}

extern "C" void kernel_launch(void* const* d_in, const int* in_sizes, int n_in,
                              void* d_out, int out_size, void* d_ws, size_t ws_size,
                              hipStream_t stream) {
  const float* outputs = (const float*)d_in[0];
  const float* targets = (const float*)d_in[1];
  float* out = (float*)d_out;
  char* ws = (char*)d_ws;

  unsigned short* ohat = (unsigned short*)ws;                                   // 8 MB
  unsigned short* that = (unsigned short*)(ws + (size_t)8 * 1024 * 1024);       // 8 MB
  float* partial       = (float*)(ws + (size_t)16 * 1024 * 1024);               // 16 MB
  float* rowloss       = (float*)(ws + (size_t)32 * 1024 * 1024);               // 64 KB

  normalize_rows<<<BROWS / 4, 256, 0, stream>>>(outputs, ohat);
  normalize_rows<<<BROWS / 4, 256, 0, stream>>>(targets, that);
  gemm_expsum<<<NBM * (BROWS / BN), 256, 0, stream>>>(ohat, that, partial);
  row_finish<<<BROWS / 4, 256, 0, stream>>>(ohat, that, partial, rowloss);
  final_reduce<<<1, 1024, 0, stream>>>(rowloss, out);
}